// Round 1
// baseline (294.481 us; speedup 1.0000x reference)
//
#include <hip/hip_runtime.h>
#include <hip/hip_bf16.h>
#include <cfloat>
#include <math.h>

#define BINS   50
#define NBINS2 2500      // 50^2
#define NBINS4 6250000   // 50^4

// ---- monotone float<->uint encoding for atomic min/max on floats ----
__device__ __forceinline__ unsigned encf(float f) {
  unsigned u = __float_as_uint(f);
  return (u & 0x80000000u) ? ~u : (u | 0x80000000u);
}
__device__ __forceinline__ float decf(unsigned u) {
  unsigned v = (u & 0x80000000u) ? (u & 0x7FFFFFFFu) : ~u;
  return __uint_as_float(v);
}

// samples = z @ L^T + mean  (L lower-triangular, row-major 4x4)
__device__ __forceinline__ void sample4(float4 zv, const float* L, const float* M,
                                        float& s0, float& s1, float& s2, float& s3) {
  s0 = L[0] * zv.x + M[0];
  s1 = fmaf(L[5], zv.y, L[4] * zv.x) + M[1];
  s2 = fmaf(L[10], zv.z, fmaf(L[9], zv.y, L[8] * zv.x)) + M[2];
  s3 = fmaf(L[15], zv.w, fmaf(L[14], zv.z, fmaf(L[13], zv.y, L[12] * zv.x))) + M[3];
}

// ---------------------------------------------------------------- init
__global__ void k_init(int* histJ, int* histQ, int* histR,
                       double* acc, double* sumJ, unsigned* encs) {
  int gid = blockIdx.x * blockDim.x + threadIdx.x;
  int stride = gridDim.x * blockDim.x;
  for (int i = gid; i < NBINS4; i += stride) histJ[i] = 0;
  if (gid < NBINS2) { histQ[gid] = 0; histR[gid] = 0; }
  if (gid < 14) acc[gid] = 0.0;
  if (gid == 14) sumJ[0] = 0.0;
  if (gid == 15) {
    encs[0] = 0xFFFFFFFFu; encs[1] = 0u;   // samples min/max
    encs[2] = 0xFFFFFFFFu; encs[3] = 0u;   // query  min/max
    encs[4] = 0xFFFFFFFFu; encs[5] = 0u;   // result min/max
  }
}

// ------------------------------------------------- raw moments (double)
__global__ void k_cov(const float* __restrict__ q, const float* __restrict__ r,
                      int n, double* acc) {
  double s0 = 0, s1 = 0, s2 = 0, s3 = 0;
  double p[10] = {0, 0, 0, 0, 0, 0, 0, 0, 0, 0};
  int stride = gridDim.x * blockDim.x;
  for (int i = blockIdx.x * blockDim.x + threadIdx.x; i < n; i += stride) {
    float2 qv = reinterpret_cast<const float2*>(q)[i];
    float2 rv = reinterpret_cast<const float2*>(r)[i];
    double x0 = qv.x, x1 = qv.y, x2 = rv.x, x3 = rv.y;
    s0 += x0; s1 += x1; s2 += x2; s3 += x3;
    p[0] += x0 * x0; p[1] += x0 * x1; p[2] += x0 * x2; p[3] += x0 * x3;
    p[4] += x1 * x1; p[5] += x1 * x2; p[6] += x1 * x3;
    p[7] += x2 * x2; p[8] += x2 * x3; p[9] += x3 * x3;
  }
  double vals[14] = {s0, s1, s2, s3, p[0], p[1], p[2], p[3], p[4],
                     p[5], p[6], p[7], p[8], p[9]};
  __shared__ double sh[4][14];
  int lane = threadIdx.x & 63, wid = threadIdx.x >> 6;
  for (int j = 0; j < 14; j++) {
    double v = vals[j];
    for (int o = 32; o > 0; o >>= 1) v += __shfl_down(v, o);
    if (lane == 0) sh[wid][j] = v;
  }
  __syncthreads();
  if (threadIdx.x < 14) {
    double t = sh[0][threadIdx.x] + sh[1][threadIdx.x] + sh[2][threadIdx.x] + sh[3][threadIdx.x];
    atomicAdd(&acc[threadIdx.x], t);
  }
}

// ------------------------------------------ finalize cov + 4x4 Cholesky
__global__ void k_chol(const double* acc, int n, float* meanf, float* Lf) {
  if (threadIdx.x != 0 || blockIdx.x != 0) return;
  double mean[4];
  for (int j = 0; j < 4; j++) mean[j] = acc[j] / (double)n;
  double cov[4][4];
  int t = 4;
  for (int i = 0; i < 4; i++)
    for (int j = i; j < 4; j++) {
      double c = (acc[t] - (double)n * mean[i] * mean[j]) / (double)(n - 1);
      if (i == j) c += 1e-6;
      cov[i][j] = c; cov[j][i] = c; t++;
    }
  double L[4][4] = {};
  for (int i = 0; i < 4; i++)
    for (int j = 0; j <= i; j++) {
      double s = cov[i][j];
      for (int k = 0; k < j; k++) s -= L[i][k] * L[j][k];
      if (i == j) L[i][j] = sqrt(s);
      else        L[i][j] = s / L[j][j];
    }
  for (int i = 0; i < 4; i++) {
    meanf[i] = (float)mean[i];
    for (int j = 0; j < 4; j++) Lf[i * 4 + j] = (float)L[i][j];
  }
}

// ------------------------------------------------- samples min/max pass
__global__ void k_sminmax(const float* __restrict__ z, int S,
                          const float* meanf, const float* Lf, unsigned* encs) {
  __shared__ float sL[16], sM[4];
  if (threadIdx.x < 16) sL[threadIdx.x] = Lf[threadIdx.x];
  if (threadIdx.x < 4) sM[threadIdx.x] = meanf[threadIdx.x];
  __syncthreads();
  float mn = FLT_MAX, mx = -FLT_MAX;
  int stride = gridDim.x * blockDim.x;
  for (int i = blockIdx.x * blockDim.x + threadIdx.x; i < S; i += stride) {
    float4 zv = reinterpret_cast<const float4*>(z)[i];
    float s0, s1, s2, s3;
    sample4(zv, sL, sM, s0, s1, s2, s3);
    mn = fminf(mn, fminf(fminf(s0, s1), fminf(s2, s3)));
    mx = fmaxf(mx, fmaxf(fmaxf(s0, s1), fmaxf(s2, s3)));
  }
  for (int o = 32; o > 0; o >>= 1) {
    mn = fminf(mn, __shfl_down(mn, o));
    mx = fmaxf(mx, __shfl_down(mx, o));
  }
  __shared__ float shmn[4], shmx[4];
  int lane = threadIdx.x & 63, wid = threadIdx.x >> 6;
  if (lane == 0) { shmn[wid] = mn; shmx[wid] = mx; }
  __syncthreads();
  if (threadIdx.x == 0) {
    mn = fminf(fminf(shmn[0], shmn[1]), fminf(shmn[2], shmn[3]));
    mx = fmaxf(fmaxf(shmx[0], shmx[1]), fmaxf(shmx[2], shmx[3]));
    atomicMin(&encs[0], encf(mn));
    atomicMax(&encs[1], encf(mx));
  }
}

// ------------------------------------------------ joint histogram (50^4)
__global__ void k_histJ(const float* __restrict__ z, int S,
                        const float* meanf, const float* Lf,
                        const unsigned* encs, int* histJ) {
  __shared__ float sL[16], sM[4], sPar[2];  // sPar: lo, scale
  if (threadIdx.x < 16) sL[threadIdx.x] = Lf[threadIdx.x];
  if (threadIdx.x < 4) sM[threadIdx.x] = meanf[threadIdx.x];
  if (threadIdx.x == 0) {
    float lo = decf(encs[0]), hi = decf(encs[1]);
    sPar[0] = lo;
    sPar[1] = (float)BINS / (hi - lo);
  }
  __syncthreads();
  float lo = sPar[0], sc = sPar[1];
  int stride = gridDim.x * blockDim.x;
  for (int i = blockIdx.x * blockDim.x + threadIdx.x; i < S; i += stride) {
    float4 zv = reinterpret_cast<const float4*>(z)[i];
    float s0, s1, s2, s3;
    sample4(zv, sL, sM, s0, s1, s2, s3);
    int i0 = min(max((int)floorf((s0 - lo) * sc), 0), BINS - 1);
    int i1 = min(max((int)floorf((s1 - lo) * sc), 0), BINS - 1);
    int i2 = min(max((int)floorf((s2 - lo) * sc), 0), BINS - 1);
    int i3 = min(max((int)floorf((s3 - lo) * sc), 0), BINS - 1);
    int flat = ((i0 * BINS + i1) * BINS + i2) * BINS + i3;
    atomicAdd(&histJ[flat], 1);
  }
}

// ------------------------------------------- joint entropy partial sums
__global__ void k_entJ(const int* __restrict__ histJ, double* sumJ) {
  double local = 0.0;
  int stride = gridDim.x * blockDim.x;
  for (int i = blockIdx.x * blockDim.x + threadIdx.x; i < NBINS4; i += stride) {
    int c = histJ[i];
    if (c > 1) local += (double)c * log((double)c);  // c==1 contributes 0
  }
  for (int o = 32; o > 0; o >>= 1) local += __shfl_down(local, o);
  __shared__ double sh[4];
  int lane = threadIdx.x & 63, wid = threadIdx.x >> 6;
  if (lane == 0) sh[wid] = local;
  __syncthreads();
  if (threadIdx.x == 0) atomicAdd(sumJ, sh[0] + sh[1] + sh[2] + sh[3]);
}

// --------------------------------------------- q / r min-max (separate)
__global__ void k_qrminmax(const float* __restrict__ q, const float* __restrict__ r,
                           int n, unsigned* encs) {
  int n4 = (n * 2) / 4;  // flat float4 count
  float qmn = FLT_MAX, qmx = -FLT_MAX, rmn = FLT_MAX, rmx = -FLT_MAX;
  int stride = gridDim.x * blockDim.x;
  for (int i = blockIdx.x * blockDim.x + threadIdx.x; i < n4; i += stride) {
    float4 v = reinterpret_cast<const float4*>(q)[i];
    qmn = fminf(qmn, fminf(fminf(v.x, v.y), fminf(v.z, v.w)));
    qmx = fmaxf(qmx, fmaxf(fmaxf(v.x, v.y), fmaxf(v.z, v.w)));
    v = reinterpret_cast<const float4*>(r)[i];
    rmn = fminf(rmn, fminf(fminf(v.x, v.y), fminf(v.z, v.w)));
    rmx = fmaxf(rmx, fmaxf(fmaxf(v.x, v.y), fmaxf(v.z, v.w)));
  }
  for (int o = 32; o > 0; o >>= 1) {
    qmn = fminf(qmn, __shfl_down(qmn, o)); qmx = fmaxf(qmx, __shfl_down(qmx, o));
    rmn = fminf(rmn, __shfl_down(rmn, o)); rmx = fmaxf(rmx, __shfl_down(rmx, o));
  }
  __shared__ float sh[4][4];
  int lane = threadIdx.x & 63, wid = threadIdx.x >> 6;
  if (lane == 0) { sh[wid][0] = qmn; sh[wid][1] = qmx; sh[wid][2] = rmn; sh[wid][3] = rmx; }
  __syncthreads();
  if (threadIdx.x == 0) {
    qmn = fminf(fminf(sh[0][0], sh[1][0]), fminf(sh[2][0], sh[3][0]));
    qmx = fmaxf(fmaxf(sh[0][1], sh[1][1]), fmaxf(sh[2][1], sh[3][1]));
    rmn = fminf(fminf(sh[0][2], sh[1][2]), fminf(sh[2][2], sh[3][2]));
    rmx = fmaxf(fmaxf(sh[0][3], sh[1][3]), fmaxf(sh[2][3], sh[3][3]));
    atomicMin(&encs[2], encf(qmn)); atomicMax(&encs[3], encf(qmx));
    atomicMin(&encs[4], encf(rmn)); atomicMax(&encs[5], encf(rmx));
  }
}

// ------------------------------------- marginal 50^2 histograms via LDS
__global__ void k_histQR(const float* __restrict__ q, const float* __restrict__ r,
                         int n, const unsigned* encs, int* histQ, int* histR) {
  __shared__ int shQ[NBINS2];
  __shared__ int shR[NBINS2];
  __shared__ float pars[4];
  for (int i = threadIdx.x; i < NBINS2; i += blockDim.x) { shQ[i] = 0; shR[i] = 0; }
  if (threadIdx.x == 0) {
    float qlo = decf(encs[2]), qhi = decf(encs[3]);
    float rlo = decf(encs[4]), rhi = decf(encs[5]);
    pars[0] = qlo; pars[1] = (float)BINS / (qhi - qlo);
    pars[2] = rlo; pars[3] = (float)BINS / (rhi - rlo);
  }
  __syncthreads();
  float qlo = pars[0], qsc = pars[1], rlo = pars[2], rsc = pars[3];
  int stride = gridDim.x * blockDim.x;
  for (int i = blockIdx.x * blockDim.x + threadIdx.x; i < n; i += stride) {
    float2 qv = reinterpret_cast<const float2*>(q)[i];
    float2 rv = reinterpret_cast<const float2*>(r)[i];
    int a = min(max((int)floorf((qv.x - qlo) * qsc), 0), BINS - 1);
    int b = min(max((int)floorf((qv.y - qlo) * qsc), 0), BINS - 1);
    atomicAdd(&shQ[a * BINS + b], 1);
    a = min(max((int)floorf((rv.x - rlo) * rsc), 0), BINS - 1);
    b = min(max((int)floorf((rv.y - rlo) * rsc), 0), BINS - 1);
    atomicAdd(&shR[a * BINS + b], 1);
  }
  __syncthreads();
  for (int i = threadIdx.x; i < NBINS2; i += blockDim.x) {
    int c = shQ[i]; if (c) atomicAdd(&histQ[i], c);
    c = shR[i];     if (c) atomicAdd(&histR[i], c);
  }
}

// --------------------------- marginal entropies + final normalized ratio
__global__ void k_final(const int* __restrict__ histQ, const int* __restrict__ histR,
                        const double* sumJ, int n, int S, float* out) {
  double lq = 0.0, lr = 0.0;
  for (int i = threadIdx.x; i < NBINS2; i += blockDim.x) {
    int c = histQ[i]; if (c > 1) lq += (double)c * log((double)c);
    c = histR[i];     if (c > 1) lr += (double)c * log((double)c);
  }
  for (int o = 32; o > 0; o >>= 1) { lq += __shfl_down(lq, o); lr += __shfl_down(lr, o); }
  __shared__ double shq[4], shr[4];
  int lane = threadIdx.x & 63, wid = threadIdx.x >> 6;
  if (lane == 0) { shq[wid] = lq; shr[wid] = lr; }
  __syncthreads();
  if (threadIdx.x == 0) {
    double sq = shq[0] + shq[1] + shq[2] + shq[3];
    double sr = shr[0] + shr[1] + shr[2] + shr[3];
    double HT = log((double)n) - sq / (double)n;
    double HI = log((double)n) - sr / (double)n;
    double HJ = log((double)S) - sumJ[0] / (double)S;
    double v = HJ / (HT + HI);
    v = v < 0.0 ? 0.0 : (v > 1.0 ? 1.0 : v);
    out[0] = (float)v;
  }
}

extern "C" void kernel_launch(void* const* d_in, const int* in_sizes, int n_in,
                              void* d_out, int out_size, void* d_ws, size_t ws_size,
                              hipStream_t stream) {
  const float* q = (const float*)d_in[0];
  const float* r = (const float*)d_in[1];
  const float* z = (const float*)d_in[2];
  int N = in_sizes[0] / 2;  // 200000 rows
  int S = in_sizes[2] / 4;  // 2000000 samples

  // workspace layout (bytes):
  //   0..112    double acc[14]   (sum4 + upper-tri products)
  // 112..120    double sumJ
  // 120..136    float mean[4]
  // 136..200    float L[16]
  // 200..224    unsigned encs[6] (Smin,Smax,Qmin,Qmax,Rmin,Rmax)
  // 256..10256  int histQ[2500]
  // 10496..20496 int histR[2500]
  // 20736..     int histJ[6250000]  (25 MB)
  char* base = (char*)d_ws;
  double*   acc   = (double*)base;
  double*   sumJ  = (double*)(base + 112);
  float*    meanf = (float*)(base + 120);
  float*    Lf    = (float*)(base + 136);
  unsigned* encs  = (unsigned*)(base + 200);
  int*      histQ = (int*)(base + 256);
  int*      histR = (int*)(base + 10496);
  int*      histJ = (int*)(base + 20736);

  k_init<<<2048, 256, 0, stream>>>(histJ, histQ, histR, acc, sumJ, encs);
  k_cov<<<256, 256, 0, stream>>>(q, r, N, acc);
  k_chol<<<1, 64, 0, stream>>>(acc, N, meanf, Lf);
  k_sminmax<<<2048, 256, 0, stream>>>(z, S, meanf, Lf, encs);
  k_histJ<<<2048, 256, 0, stream>>>(z, S, meanf, Lf, encs, histJ);
  k_entJ<<<2048, 256, 0, stream>>>(histJ, sumJ);
  k_qrminmax<<<256, 256, 0, stream>>>(q, r, N, encs);
  k_histQR<<<64, 256, 0, stream>>>(q, r, N, encs, histQ, histR);
  k_final<<<1, 256, 0, stream>>>(histQ, histR, sumJ, N, S, (float*)d_out);
}